// Round 5
// baseline (141.668 us; speedup 1.0000x reference)
//
#include <hip/hip_runtime.h>
#include <hip/hip_bf16.h>
#include <hip/hip_fp8.h>
#include <math.h>

typedef __attribute__((ext_vector_type(4))) int   int4v;
typedef __attribute__((ext_vector_type(8))) int   int8v;
typedef __attribute__((ext_vector_type(4))) float f32x4;

#define AS1 __attribute__((address_space(1)))
#define AS3 __attribute__((address_space(3)))

// ---------------------------------------------------------------------------
// prep: grid-stride, one wave per row per iter. fp32 -> fp8 e4m3 (OCP) +
// exact fp32 ||row||^2. Also zeroes rowsum[M].
// ---------------------------------------------------------------------------
__global__ __launch_bounds__(256) void prep_kernel(
    const float* __restrict__ X, const float* __restrict__ S,
    unsigned char* __restrict__ Xq, unsigned char* __restrict__ Sq,
    float* __restrict__ x2, float* __restrict__ s2,
    float* __restrict__ rowsum, int M, int R, int Dv)
{
    const int gid  = blockIdx.x * 256 + threadIdx.x;
    const int nthr = gridDim.x * 256;

    for (int i = gid; i < M; i += nthr) rowsum[i] = 0.f;

    const int lane = threadIdx.x & 63;
    const int wid  = gid >> 6;
    const int nw   = nthr >> 6;

    for (int row = wid; row < R; row += nw) {
        const float* rp;
        unsigned char* op;
        float* sq;
        if (row < M) { rp = X + (size_t)row * Dv;       op = Xq + (size_t)row * Dv;       sq = x2 + row; }
        else         { rp = S + (size_t)(row - M) * Dv; op = Sq + (size_t)(row - M) * Dv; sq = s2 + (row - M); }

        float acc = 0.f;
        for (int k = lane * 8; k < Dv; k += 64 * 8) {
            float4 v0 = *(const float4*)(rp + k);
            float4 v1 = *(const float4*)(rp + k + 4);
            acc += v0.x * v0.x + v0.y * v0.y + v0.z * v0.z + v0.w * v0.w;
            acc += v1.x * v1.x + v1.y * v1.y + v1.z * v1.z + v1.w * v1.w;
            union { __hip_fp8_e4m3 h[8]; uint2 u; } pk;
            pk.h[0] = __hip_fp8_e4m3(v0.x);
            pk.h[1] = __hip_fp8_e4m3(v0.y);
            pk.h[2] = __hip_fp8_e4m3(v0.z);
            pk.h[3] = __hip_fp8_e4m3(v0.w);
            pk.h[4] = __hip_fp8_e4m3(v1.x);
            pk.h[5] = __hip_fp8_e4m3(v1.y);
            pk.h[6] = __hip_fp8_e4m3(v1.z);
            pk.h[7] = __hip_fp8_e4m3(v1.w);
            *(uint2*)(op + k) = pk.u;
        }
#pragma unroll
        for (int off = 1; off < 64; off <<= 1)
            acc += __shfl_xor(acc, off, 64);
        if (lane == 0) *sq = acc;
    }
}

// ---------------------------------------------------------------------------
// D=512 specialized: barrier-free K. Block = 256 thr (4 waves), tile 128x128.
// A (32 rows/wave, full K=512) in REGISTERS: af[2][4], 32 B/lane/fragment,
// loaded directly from global (no LDS, no barrier dependency).
// B (128 rows x 512 B = 64 KB) staged once in LDS, 16-B-chunk XOR swizzle
// phys = c ^ (row&7); staging thread t -> row t>>5, phys chunk t&31, global
// chunk (t&31)^(t>>5)  [linear-lane rule satisfied].
// After ONE barrier: 64 MFMA + 64 ds_read_b128 per wave, no further syncs.
// ---------------------------------------------------------------------------
__global__ __launch_bounds__(256, 2) void kde_gemm512(
    const unsigned char* __restrict__ Xq,   // [M][512] fp8 e4m3
    const unsigned char* __restrict__ Sq,   // [N][512] fp8 e4m3
    const float* __restrict__ x2,
    const float* __restrict__ s2,
    const float* __restrict__ scale_p,
    float* __restrict__ rowsum,
    int M, int N)
{
    __shared__ char smem[65536];
    unsigned char* Bs = (unsigned char*)smem;  // [128][512] fp8, chunk-swizzled

    const int tid  = threadIdx.x;
    const int wave = tid >> 6;
    const int lane = tid & 63;
    const int quad = lane >> 4;
    const int l16  = lane & 15;

    const int m0 = blockIdx.x * 128;
    const int n0 = blockIdx.y * 128;

    const float sc = *scale_p;

    // ---- B staging: 16 rounds x 4096 B (8 rows each). row&7 == t>>5.
    const int srow = tid >> 5;                 // 0..7
    const int cg   = (tid & 31) ^ srow;        // global chunk for phys t&31
    const unsigned char* gB = Sq + (size_t)(n0 + srow) * 512 + cg * 16;
#pragma unroll
    for (int r = 0; r < 16; ++r)
        __builtin_amdgcn_global_load_lds(
            (const AS1 void*)(gB + (size_t)r * 8 * 512),
            (AS3 void*)(smem + r * 4096 + wave * 1024),
            16, 0, 0);

    // ---- A register loads (independent of the barrier). Lane (q,l16) holds
    // bytes [c*128 + q*32, +32) of row m0 + wave*32 + mi*16 + l16.
    int8v af[2][4];
    const unsigned char* gA = Xq + (size_t)(m0 + wave * 32 + l16) * 512 + quad * 32;
#pragma unroll
    for (int mi = 0; mi < 2; ++mi)
#pragma unroll
        for (int c = 0; c < 4; ++c) {
            int4v lo = *(const int4v*)(gA + mi * 16 * 512 + c * 128);
            int4v hi = *(const int4v*)(gA + mi * 16 * 512 + c * 128 + 16);
            af[mi][c] = (int8v){lo.x, lo.y, lo.z, lo.w, hi.x, hi.y, hi.z, hi.w};
        }

    f32x4 acc[2][8] = {};

    __syncthreads();  // the ONLY pre-compute barrier (drains staging + A loads)

    // ---- barrier-free MFMA block: 64 MFMA + 64 ds_read_b128 per wave.
    const int e = l16 & 7;
#pragma unroll
    for (int c = 0; c < 4; ++c) {
#pragma unroll
        for (int ni = 0; ni < 8; ++ni) {
            const unsigned char* rowp = Bs + (size_t)(ni * 16 + l16) * 512;
            int4v lo = *(const int4v*)(rowp + (8 * c + ((2 * quad)     ^ e)) * 16);
            int4v hi = *(const int4v*)(rowp + (8 * c + ((2 * quad + 1) ^ e)) * 16);
            int8v bf = (int8v){lo.x, lo.y, lo.z, lo.w, hi.x, hi.y, hi.z, hi.w};
            acc[0][ni] = __builtin_amdgcn_mfma_scale_f32_16x16x128_f8f6f4(
                af[0][c], bf, acc[0][ni], 0, 0, 0, 0x7F7F7F7F, 0, 0x7F7F7F7F);
            acc[1][ni] = __builtin_amdgcn_mfma_scale_f32_16x16x128_f8f6f4(
                af[1][c], bf, acc[1][ni], 0, 0, 0, 0x7F7F7F7F, 0, 0x7F7F7F7F);
        }
    }

    // ---- epilogue. C layout: col = l16 (-> n), row = quad*4 + reg (-> m).
    __syncthreads();  // all waves done reading Bs; reuse LDS for reduction
    float* wred = (float*)smem + wave * (32 * 20);  // 2560 B per wave

    float s2v[8];
#pragma unroll
    for (int ni = 0; ni < 8; ++ni)
        s2v[ni] = s2[n0 + ni * 16 + l16];

#pragma unroll
    for (int mi = 0; mi < 2; ++mi) {
#pragma unroll
        for (int r = 0; r < 4; ++r) {
            const int rl = mi * 16 + quad * 4 + r;         // 0..31 within wave
            const float xv = x2[m0 + wave * 32 + rl];
            float sum = 0.f;
#pragma unroll
            for (int ni = 0; ni < 8; ++ni) {
                float d2 = xv + s2v[ni] - 2.0f * acc[mi][ni][r];
                d2 = fmaxf(d2, 0.f);
                sum += __expf(-sc * d2);
            }
            wred[rl * 20 + l16] = sum;
        }
    }
    __syncthreads();  // order LDS writes before cross-lane reads

    if (lane < 32) {
        float* rp = wred + lane * 20;
        float4 p0 = *(float4*)(rp + 0);
        float4 p1 = *(float4*)(rp + 4);
        float4 p2 = *(float4*)(rp + 8);
        float4 p3 = *(float4*)(rp + 12);
        float s = (p0.x + p0.y + p0.z + p0.w) + (p1.x + p1.y + p1.z + p1.w)
                + (p2.x + p2.y + p2.z + p2.w) + (p3.x + p3.y + p3.z + p3.w);
        atomicAdd(&rowsum[m0 + wave * 32 + lane], s);
    }
}

// ---------------------------------------------------------------------------
// Generic-D fallback (R4 structure, verified): 2-barrier K-loop, BK=128.
// ---------------------------------------------------------------------------
__global__ __launch_bounds__(256, 3) void kde_gemm_generic(
    const unsigned char* __restrict__ Xq, const unsigned char* __restrict__ Sq,
    const float* __restrict__ x2, const float* __restrict__ s2,
    const float* __restrict__ scale_p, float* __restrict__ rowsum,
    int M, int N, int Dv)
{
    const int D = Dv;
    __shared__ char smem[32768];
    unsigned char* As = (unsigned char*)smem;
    unsigned char* Bs = (unsigned char*)(smem + 16384);

    const int tid  = threadIdx.x;
    const int wave = tid >> 6;
    const int lane = tid & 63;
    const int quad = lane >> 4;
    const int l16  = lane & 15;

    const int m0 = blockIdx.x * 128;
    const int n0 = blockIdx.y * 128;
    const int wm = (wave & 1) * 64;
    const int wn = (wave >> 1) * 64;

    const float sc = *scale_p;
    f32x4 acc[4][4] = {};

    const int srow0 = wave * 8 + (lane >> 3);
    const int cg    = (lane & 7) ^ (lane >> 3);
    const unsigned char* gA = Xq + (size_t)(m0 + srow0) * D + cg * 16;
    const unsigned char* gB = Sq + (size_t)(n0 + srow0) * D + cg * 16;

    for (int k0 = 0; k0 < D; k0 += 128) {
        __syncthreads();
#pragma unroll
        for (int rd = 0; rd < 4; ++rd)
            __builtin_amdgcn_global_load_lds(
                (const AS1 void*)(gA + (size_t)rd * 32 * D + k0),
                (AS3 void*)(smem + rd * 4096 + wave * 1024), 16, 0, 0);
#pragma unroll
        for (int rd = 0; rd < 4; ++rd)
            __builtin_amdgcn_global_load_lds(
                (const AS1 void*)(gB + (size_t)rd * 32 * D + k0),
                (AS3 void*)(smem + 16384 + rd * 4096 + wave * 1024), 16, 0, 0);
        __syncthreads();

        const int e = l16 & 7;
        int8v a_frag[4], b_frag[4];
#pragma unroll
        for (int mi = 0; mi < 4; ++mi) {
            const unsigned char* rowp = As + (wm + mi * 16 + l16) * 128;
            int4v lo = *(const int4v*)(rowp + ((2 * quad)     ^ e) * 16);
            int4v hi = *(const int4v*)(rowp + ((2 * quad + 1) ^ e) * 16);
            a_frag[mi] = (int8v){lo.x, lo.y, lo.z, lo.w, hi.x, hi.y, hi.z, hi.w};
        }
#pragma unroll
        for (int ni = 0; ni < 4; ++ni) {
            const unsigned char* rowp = Bs + (wn + ni * 16 + l16) * 128;
            int4v lo = *(const int4v*)(rowp + ((2 * quad)     ^ e) * 16);
            int4v hi = *(const int4v*)(rowp + ((2 * quad + 1) ^ e) * 16);
            b_frag[ni] = (int8v){lo.x, lo.y, lo.z, lo.w, hi.x, hi.y, hi.z, hi.w};
        }
#pragma unroll
        for (int mi = 0; mi < 4; ++mi)
#pragma unroll
            for (int ni = 0; ni < 4; ++ni)
                acc[mi][ni] = __builtin_amdgcn_mfma_scale_f32_16x16x128_f8f6f4(
                    a_frag[mi], b_frag[ni], acc[mi][ni],
                    0, 0, 0, 0x7F7F7F7F, 0, 0x7F7F7F7F);
    }

    __syncthreads();
    float* wred = (float*)smem + wave * (64 * 20);

    float s2v[4];
#pragma unroll
    for (int ni = 0; ni < 4; ++ni)
        s2v[ni] = s2[n0 + wn + ni * 16 + l16];

#pragma unroll
    for (int mi = 0; mi < 4; ++mi) {
#pragma unroll
        for (int r = 0; r < 4; ++r) {
            const int rowL = mi * 16 + quad * 4 + r;
            const float xv = x2[m0 + wm + rowL];
            float sum = 0.f;
#pragma unroll
            for (int ni = 0; ni < 4; ++ni) {
                float d2 = xv + s2v[ni] - 2.0f * acc[mi][ni][r];
                d2 = fmaxf(d2, 0.f);
                sum += __expf(-sc * d2);
            }
            wred[rowL * 20 + l16] = sum;
        }
    }
    __syncthreads();

    float4 p0 = *(float4*)(wred + lane * 20 + 0);
    float4 p1 = *(float4*)(wred + lane * 20 + 4);
    float4 p2 = *(float4*)(wred + lane * 20 + 8);
    float4 p3 = *(float4*)(wred + lane * 20 + 12);
    float s = (p0.x + p0.y + p0.z + p0.w) + (p1.x + p1.y + p1.z + p1.w)
            + (p2.x + p2.y + p2.z + p2.w) + (p3.x + p3.y + p3.z + p3.w);
    atomicAdd(&rowsum[m0 + wm + lane], s);
}

// ---------------------------------------------------------------------------
__global__ void finalize_kernel(const float* __restrict__ rowsum,
                                const float* __restrict__ scale_p,
                                float* __restrict__ out, int M, int N, int Dv) {
    const int m = blockIdx.x * 256 + threadIdx.x;
    if (m < M) {
        const float sc = *scale_p;
        const float cst = -logf((float)N) + 0.5f * (float)Dv * logf(sc / 3.14159265358979f);
        out[m] = logf(rowsum[m]) + cst;
    }
}

// ---------------------------------------------------------------------------
extern "C" void kernel_launch(void* const* d_in, const int* in_sizes, int n_in,
                              void* d_out, int out_size, void* d_ws, size_t ws_size,
                              hipStream_t stream) {
    const float* X       = (const float*)d_in[0];
    const float* S       = (const float*)d_in[1];
    const float* scale_p = (const float*)d_in[2];
    float* out = (float*)d_out;

    const int M  = out_size;            // 8192
    const int Dv = in_sizes[0] / M;     // 512
    const int N  = in_sizes[1] / Dv;    // 8192

    char* ws = (char*)d_ws;
    unsigned char* Xq = (unsigned char*)ws;
    unsigned char* Sq = (unsigned char*)(ws + (size_t)M * Dv);
    float* x2     = (float*)(ws + (size_t)M * Dv + (size_t)N * Dv);
    float* s2     = x2 + M;
    float* rowsum = s2 + N;

    prep_kernel<<<512, 256, 0, stream>>>(X, S, Xq, Sq, x2, s2, rowsum, M, M + N, Dv);

    dim3 grid(M / 128, N / 128);
    if (Dv == 512)
        kde_gemm512<<<grid, 256, 0, stream>>>(Xq, Sq, x2, s2, scale_p, rowsum, M, N);
    else
        kde_gemm_generic<<<grid, 256, 0, stream>>>(Xq, Sq, x2, s2, scale_p, rowsum, M, N, Dv);

    finalize_kernel<<<(M + 255) / 256, 256, 0, stream>>>(rowsum, scale_p, out, M, N, Dv);
}

// Round 6
// 123.505 us; speedup vs baseline: 1.1471x; 1.1471x over previous
//
#include <hip/hip_runtime.h>
#include <hip/hip_bf16.h>
#include <hip/hip_fp8.h>
#include <math.h>

typedef __attribute__((ext_vector_type(4))) int   int4v;
typedef __attribute__((ext_vector_type(8))) int   int8v;
typedef __attribute__((ext_vector_type(4))) float f32x4;

#define AS1 __attribute__((address_space(1)))
#define AS3 __attribute__((address_space(3)))

// ---------------------------------------------------------------------------
// prep: grid-stride, one wave per row per iter. fp32 -> fp8 e4m3 (OCP) +
// exact fp32 ||row||^2. Also zeroes rowsum[M].
// ---------------------------------------------------------------------------
__global__ __launch_bounds__(256) void prep_kernel(
    const float* __restrict__ X, const float* __restrict__ S,
    unsigned char* __restrict__ Xq, unsigned char* __restrict__ Sq,
    float* __restrict__ x2, float* __restrict__ s2,
    float* __restrict__ rowsum, int M, int R, int Dv)
{
    const int gid  = blockIdx.x * 256 + threadIdx.x;
    const int nthr = gridDim.x * 256;

    for (int i = gid; i < M; i += nthr) rowsum[i] = 0.f;

    const int lane = threadIdx.x & 63;
    const int wid  = gid >> 6;
    const int nw   = nthr >> 6;

    for (int row = wid; row < R; row += nw) {
        const float* rp;
        unsigned char* op;
        float* sq;
        if (row < M) { rp = X + (size_t)row * Dv;       op = Xq + (size_t)row * Dv;       sq = x2 + row; }
        else         { rp = S + (size_t)(row - M) * Dv; op = Sq + (size_t)(row - M) * Dv; sq = s2 + (row - M); }

        float acc = 0.f;
        for (int k = lane * 8; k < Dv; k += 64 * 8) {
            float4 v0 = *(const float4*)(rp + k);
            float4 v1 = *(const float4*)(rp + k + 4);
            acc += v0.x * v0.x + v0.y * v0.y + v0.z * v0.z + v0.w * v0.w;
            acc += v1.x * v1.x + v1.y * v1.y + v1.z * v1.z + v1.w * v1.w;
            union { __hip_fp8_e4m3 h[8]; uint2 u; } pk;
            pk.h[0] = __hip_fp8_e4m3(v0.x);
            pk.h[1] = __hip_fp8_e4m3(v0.y);
            pk.h[2] = __hip_fp8_e4m3(v0.z);
            pk.h[3] = __hip_fp8_e4m3(v0.w);
            pk.h[4] = __hip_fp8_e4m3(v1.x);
            pk.h[5] = __hip_fp8_e4m3(v1.y);
            pk.h[6] = __hip_fp8_e4m3(v1.z);
            pk.h[7] = __hip_fp8_e4m3(v1.w);
            *(uint2*)(op + k) = pk.u;
        }
#pragma unroll
        for (int off = 1; off < 64; off <<= 1)
            acc += __shfl_xor(acc, off, 64);
        if (lane == 0) *sq = acc;
    }
}

// ---------------------------------------------------------------------------
// D=512 fused fp8 GEMM + exp-reduce, DOUBLE-BUFFERED LDS.
// 256 thr (4 waves 2x2), tile 128x128, BK=128, 4 K-iters.
// Pipeline: stage(0); for k: { sync; issue stage(k+1) -> other buf;
// compute(k) }. The vmcnt(0) drain at each sync lands one full compute
// phase after issue -> drain ~free. 2x32 KB LDS, 2 blocks/CU.
// LDS 16B-chunk XOR swizzle phys = c ^ (row&7) (R2-verified staging map).
// ---------------------------------------------------------------------------
__global__ __launch_bounds__(256, 2) void kde_gemm512(
    const unsigned char* __restrict__ Xq,   // [M][512] fp8 e4m3
    const unsigned char* __restrict__ Sq,   // [N][512] fp8 e4m3
    const float* __restrict__ x2,
    const float* __restrict__ s2,
    const float* __restrict__ scale_p,
    float* __restrict__ rowsum,
    int M, int N)
{
    __shared__ char smem[65536];   // buf b at b*32768: [A 16KB | B 16KB]

    const int tid  = threadIdx.x;
    const int wave = tid >> 6;
    const int lane = tid & 63;
    const int quad = lane >> 4;
    const int l16  = lane & 15;

    const int m0 = blockIdx.x * 128;
    const int n0 = blockIdx.y * 128;
    const int wm = (wave & 1) * 64;
    const int wn = (wave >> 1) * 64;

    const float sc = *scale_p;

    f32x4 acc[4][4] = {};

    // staging map (R2/R4-verified): round rd covers rows rd*32..+31;
    // thread row = wave*8 + (lane>>3) + rd*32, global chunk (lane&7)^(row&7)
    // into physical slot lane&7; LDS dst linear in lane.
    const int srow0 = wave * 8 + (lane >> 3);
    const int cg    = (lane & 7) ^ (lane >> 3);
    const unsigned char* gA = Xq + (size_t)(m0 + srow0) * 512 + cg * 16;
    const unsigned char* gB = Sq + (size_t)(n0 + srow0) * 512 + cg * 16;

    // prologue: stage k=0 into buf 0
#pragma unroll
    for (int rd = 0; rd < 4; ++rd)
        __builtin_amdgcn_global_load_lds(
            (const AS1 void*)(gA + (size_t)rd * 32 * 512),
            (AS3 void*)(smem + rd * 4096 + wave * 1024), 16, 0, 0);
#pragma unroll
    for (int rd = 0; rd < 4; ++rd)
        __builtin_amdgcn_global_load_lds(
            (const AS1 void*)(gB + (size_t)rd * 32 * 512),
            (AS3 void*)(smem + 16384 + rd * 4096 + wave * 1024), 16, 0, 0);

    const int e = l16 & 7;

#pragma unroll
    for (int k = 0; k < 4; ++k) {
        __syncthreads();   // buf[k&1] ready; everyone done reading buf[(k+1)&1]

        if (k < 3) {       // issue stage(k+1) into the other buffer
            const int k1 = (k + 1) * 128;
            char* dst = smem + ((k + 1) & 1) * 32768;
#pragma unroll
            for (int rd = 0; rd < 4; ++rd)
                __builtin_amdgcn_global_load_lds(
                    (const AS1 void*)(gA + (size_t)rd * 32 * 512 + k1),
                    (AS3 void*)(dst + rd * 4096 + wave * 1024), 16, 0, 0);
#pragma unroll
            for (int rd = 0; rd < 4; ++rd)
                __builtin_amdgcn_global_load_lds(
                    (const AS1 void*)(gB + (size_t)rd * 32 * 512 + k1),
                    (AS3 void*)(dst + 16384 + rd * 4096 + wave * 1024), 16, 0, 0);
        }

        const unsigned char* As = (const unsigned char*)(smem + (k & 1) * 32768);
        const unsigned char* Bs = As + 16384;

        int8v a_frag[4], b_frag[4];
#pragma unroll
        for (int mi = 0; mi < 4; ++mi) {
            const unsigned char* rowp = As + (wm + mi * 16 + l16) * 128;
            int4v lo = *(const int4v*)(rowp + ((2 * quad)     ^ e) * 16);
            int4v hi = *(const int4v*)(rowp + ((2 * quad + 1) ^ e) * 16);
            a_frag[mi] = (int8v){lo.x, lo.y, lo.z, lo.w, hi.x, hi.y, hi.z, hi.w};
        }
#pragma unroll
        for (int ni = 0; ni < 4; ++ni) {
            const unsigned char* rowp = Bs + (wn + ni * 16 + l16) * 128;
            int4v lo = *(const int4v*)(rowp + ((2 * quad)     ^ e) * 16);
            int4v hi = *(const int4v*)(rowp + ((2 * quad + 1) ^ e) * 16);
            b_frag[ni] = (int8v){lo.x, lo.y, lo.z, lo.w, hi.x, hi.y, hi.z, hi.w};
        }
#pragma unroll
        for (int mi = 0; mi < 4; ++mi)
#pragma unroll
            for (int ni = 0; ni < 4; ++ni)
                acc[mi][ni] = __builtin_amdgcn_mfma_scale_f32_16x16x128_f8f6f4(
                    a_frag[mi], b_frag[ni], acc[mi][ni],
                    0, 0, 0, 0x7F7F7F7F, 0, 0x7F7F7F7F);
    }

    // ---- epilogue. C layout: col = l16 (-> n), row = quad*4 + reg (-> m).
    __syncthreads();
    float* wred = (float*)smem + wave * (64 * 20);

    float s2v[4];
#pragma unroll
    for (int ni = 0; ni < 4; ++ni)
        s2v[ni] = s2[n0 + wn + ni * 16 + l16];

#pragma unroll
    for (int mi = 0; mi < 4; ++mi) {
#pragma unroll
        for (int r = 0; r < 4; ++r) {
            const int rowL = mi * 16 + quad * 4 + r;
            const float xv = x2[m0 + wm + rowL];
            float sum = 0.f;
#pragma unroll
            for (int ni = 0; ni < 4; ++ni) {
                float d2 = xv + s2v[ni] - 2.0f * acc[mi][ni][r];
                d2 = fmaxf(d2, 0.f);
                sum += __expf(-sc * d2);
            }
            wred[rowL * 20 + l16] = sum;
        }
    }
    __syncthreads();

    float4 p0 = *(float4*)(wred + lane * 20 + 0);
    float4 p1 = *(float4*)(wred + lane * 20 + 4);
    float4 p2 = *(float4*)(wred + lane * 20 + 8);
    float4 p3 = *(float4*)(wred + lane * 20 + 12);
    float s = (p0.x + p0.y + p0.z + p0.w) + (p1.x + p1.y + p1.z + p1.w)
            + (p2.x + p2.y + p2.z + p2.w) + (p3.x + p3.y + p3.z + p3.w);
    atomicAdd(&rowsum[m0 + wm + lane], s);
}

// ---------------------------------------------------------------------------
// Generic-D fallback (R4 structure, verified).
// ---------------------------------------------------------------------------
__global__ __launch_bounds__(256, 3) void kde_gemm_generic(
    const unsigned char* __restrict__ Xq, const unsigned char* __restrict__ Sq,
    const float* __restrict__ x2, const float* __restrict__ s2,
    const float* __restrict__ scale_p, float* __restrict__ rowsum,
    int M, int N, int Dv)
{
    const int D = Dv;
    __shared__ char smem[32768];
    unsigned char* As = (unsigned char*)smem;
    unsigned char* Bs = (unsigned char*)(smem + 16384);

    const int tid  = threadIdx.x;
    const int wave = tid >> 6;
    const int lane = tid & 63;
    const int quad = lane >> 4;
    const int l16  = lane & 15;

    const int m0 = blockIdx.x * 128;
    const int n0 = blockIdx.y * 128;
    const int wm = (wave & 1) * 64;
    const int wn = (wave >> 1) * 64;

    const float sc = *scale_p;
    f32x4 acc[4][4] = {};

    const int srow0 = wave * 8 + (lane >> 3);
    const int cg    = (lane & 7) ^ (lane >> 3);
    const unsigned char* gA = Xq + (size_t)(m0 + srow0) * D + cg * 16;
    const unsigned char* gB = Sq + (size_t)(n0 + srow0) * D + cg * 16;

    for (int k0 = 0; k0 < D; k0 += 128) {
        __syncthreads();
#pragma unroll
        for (int rd = 0; rd < 4; ++rd)
            __builtin_amdgcn_global_load_lds(
                (const AS1 void*)(gA + (size_t)rd * 32 * D + k0),
                (AS3 void*)(smem + rd * 4096 + wave * 1024), 16, 0, 0);
#pragma unroll
        for (int rd = 0; rd < 4; ++rd)
            __builtin_amdgcn_global_load_lds(
                (const AS1 void*)(gB + (size_t)rd * 32 * D + k0),
                (AS3 void*)(smem + 16384 + rd * 4096 + wave * 1024), 16, 0, 0);
        __syncthreads();

        const int e = l16 & 7;
        int8v a_frag[4], b_frag[4];
#pragma unroll
        for (int mi = 0; mi < 4; ++mi) {
            const unsigned char* rowp = As + (wm + mi * 16 + l16) * 128;
            int4v lo = *(const int4v*)(rowp + ((2 * quad)     ^ e) * 16);
            int4v hi = *(const int4v*)(rowp + ((2 * quad + 1) ^ e) * 16);
            a_frag[mi] = (int8v){lo.x, lo.y, lo.z, lo.w, hi.x, hi.y, hi.z, hi.w};
        }
#pragma unroll
        for (int ni = 0; ni < 4; ++ni) {
            const unsigned char* rowp = Bs + (wn + ni * 16 + l16) * 128;
            int4v lo = *(const int4v*)(rowp + ((2 * quad)     ^ e) * 16);
            int4v hi = *(const int4v*)(rowp + ((2 * quad + 1) ^ e) * 16);
            b_frag[ni] = (int8v){lo.x, lo.y, lo.z, lo.w, hi.x, hi.y, hi.z, hi.w};
        }
#pragma unroll
        for (int mi = 0; mi < 4; ++mi)
#pragma unroll
            for (int ni = 0; ni < 4; ++ni)
                acc[mi][ni] = __builtin_amdgcn_mfma_scale_f32_16x16x128_f8f6f4(
                    a_frag[mi], b_frag[ni], acc[mi][ni],
                    0, 0, 0, 0x7F7F7F7F, 0, 0x7F7F7F7F);
    }

    __syncthreads();
    float* wred = (float*)smem + wave * (64 * 20);

    float s2v[4];
#pragma unroll
    for (int ni = 0; ni < 4; ++ni)
        s2v[ni] = s2[n0 + wn + ni * 16 + l16];

#pragma unroll
    for (int mi = 0; mi < 4; ++mi) {
#pragma unroll
        for (int r = 0; r < 4; ++r) {
            const int rowL = mi * 16 + quad * 4 + r;
            const float xv = x2[m0 + wm + rowL];
            float sum = 0.f;
#pragma unroll
            for (int ni = 0; ni < 4; ++ni) {
                float d2 = xv + s2v[ni] - 2.0f * acc[mi][ni][r];
                d2 = fmaxf(d2, 0.f);
                sum += __expf(-sc * d2);
            }
            wred[rowL * 20 + l16] = sum;
        }
    }
    __syncthreads();

    float4 p0 = *(float4*)(wred + lane * 20 + 0);
    float4 p1 = *(float4*)(wred + lane * 20 + 4);
    float4 p2 = *(float4*)(wred + lane * 20 + 8);
    float4 p3 = *(float4*)(wred + lane * 20 + 12);
    float s = (p0.x + p0.y + p0.z + p0.w) + (p1.x + p1.y + p1.z + p1.w)
            + (p2.x + p2.y + p2.z + p2.w) + (p3.x + p3.y + p3.z + p3.w);
    atomicAdd(&rowsum[m0 + wm + lane], s);
}

// ---------------------------------------------------------------------------
__global__ void finalize_kernel(const float* __restrict__ rowsum,
                                const float* __restrict__ scale_p,
                                float* __restrict__ out, int M, int N, int Dv) {
    const int m = blockIdx.x * 256 + threadIdx.x;
    if (m < M) {
        const float sc = *scale_p;
        const float cst = -logf((float)N) + 0.5f * (float)Dv * logf(sc / 3.14159265358979f);
        out[m] = logf(rowsum[m]) + cst;
    }
}

// ---------------------------------------------------------------------------
extern "C" void kernel_launch(void* const* d_in, const int* in_sizes, int n_in,
                              void* d_out, int out_size, void* d_ws, size_t ws_size,
                              hipStream_t stream) {
    const float* X       = (const float*)d_in[0];
    const float* S       = (const float*)d_in[1];
    const float* scale_p = (const float*)d_in[2];
    float* out = (float*)d_out;

    const int M  = out_size;            // 8192
    const int Dv = in_sizes[0] / M;     // 512
    const int N  = in_sizes[1] / Dv;    // 8192

    char* ws = (char*)d_ws;
    unsigned char* Xq = (unsigned char*)ws;
    unsigned char* Sq = (unsigned char*)(ws + (size_t)M * Dv);
    float* x2     = (float*)(ws + (size_t)M * Dv + (size_t)N * Dv);
    float* s2     = x2 + M;
    float* rowsum = s2 + N;

    prep_kernel<<<512, 256, 0, stream>>>(X, S, Xq, Sq, x2, s2, rowsum, M, M + N, Dv);

    dim3 grid(M / 128, N / 128);
    if (Dv == 512)
        kde_gemm512<<<grid, 256, 0, stream>>>(Xq, Sq, x2, s2, scale_p, rowsum, M, N);
    else
        kde_gemm_generic<<<grid, 256, 0, stream>>>(Xq, Sq, x2, s2, scale_p, rowsum, M, N, Dv);

    finalize_kernel<<<(M + 255) / 256, 256, 0, stream>>>(rowsum, scale_p, out, M, N, Dv);
}